// Round 5
// baseline (152.976 us; speedup 1.0000x reference)
//
#include <hip/hip_runtime.h>

// Deep-Sets actor, round 5: operand-swapped MFMA -> vectorized epilogues.
// All GEMMs computed as D = W_frag x act_frag (+bias in C-init), so each lane
// holds 4 consecutive k-columns of one activation row -> cvt_pk + ds_write_b64.
// main: B/64 blocks x 512 thr (8 waves), M=64 rows, wave owns 32 N-cols.
// LDS 52224 B -> 2 blocks/CU. Weights streamed from L2.

typedef __bf16 bf16x8 __attribute__((ext_vector_type(8)));
typedef float f32x4 __attribute__((ext_vector_type(4)));
typedef unsigned short u16x8 __attribute__((ext_vector_type(8)));

#define HB_OFF   0        // hbuf: 64 rows x 512 B, XOR-swizzled      (32768)
#define INP_OFF  32768    // inp:  64 rows x 128 B, XOR-swizzled      ( 8192)
#define RAW_OFF  40960    // raw:  64 rows x 82 bf16                  (10496)
#define STAB_OFF 51456    // s-tables: 6 perms x 64 u16               (  768)
#define LDS_TOTAL 52224

__device__ __forceinline__ unsigned short f2bf(float f) {
  union { float f; unsigned u; } v; v.f = f;
  unsigned r = v.u + 0x7fffu + ((v.u >> 16) & 1u);  // RNE
  return (unsigned short)(r >> 16);
}
__device__ __forceinline__ int swz512(int o) { return o ^ (((o >> 9) & 7) << 4); }
__device__ __forceinline__ int swz128(int o) { return o ^ (((o >> 7) & 7) << 4); }
__device__ __forceinline__ f32x4 mfma16(bf16x8 a, bf16x8 b, f32x4 c) {
  return __builtin_amdgcn_mfma_f32_16x16x32_bf16(a, b, c, 0, 0, 0);
}
__device__ __forceinline__ uint2 pack4(f32x4 v) {  // 4 f32 -> 4 bf16 (RNE)
  uint2 r;
  asm("v_cvt_pk_bf16_f32 %0, %1, %2" : "=v"(r.x) : "v"(v[0]), "v"(v[1]));
  asm("v_cvt_pk_bf16_f32 %0, %1, %2" : "=v"(r.y) : "v"(v[2]), "v"(v[3]));
  return r;
}

__global__ void actor_prep(const float* __restrict__ w1, const float* __restrict__ w2,
                           const float* __restrict__ rho, const float* __restrict__ mw,
                           const float* __restrict__ lw, unsigned short* __restrict__ ws16) {
  int idx = blockIdx.x * blockDim.x + threadIdx.x;
  const int T = 16384 + 65536 + 65536 + 4096;
  for (; idx < T; idx += gridDim.x * blockDim.x) {
    float v;
    if (idx < 16384) {                 // W1T[n][k], k padded 58->64
      int n = idx >> 6, k = idx & 63;
      v = (k < 58) ? w1[k * 256 + n] : 0.f;
    } else if (idx < 81920) {          // W2T[n][k]
      int o = idx - 16384; int n = o >> 8, k = o & 255;
      v = w2[k * 256 + n];
    } else if (idx < 147456) {         // RHOT[n][k]
      int o = idx - 81920; int n = o >> 8, k = o & 255;
      v = rho[k * 256 + n];
    } else {                           // HEADT[n][k]
      int o = idx - 147456; int n = o >> 8, k = o & 255;
      v = (n < 4) ? mw[k * 4 + n] : ((n < 8) ? lw[k * 4 + (n - 4)] : 0.f);
    }
    ws16[idx] = f2bf(v);
  }
}

__global__ __launch_bounds__(512, 2) void actor_main(
    const float* __restrict__ obs, const float* __restrict__ ag, const float* __restrict__ g,
    const float* __restrict__ b1v, const float* __restrict__ b2v, const float* __restrict__ rbv,
    const float* __restrict__ mbv, const float* __restrict__ lbv,
    const unsigned short* __restrict__ ws16,
    float* __restrict__ out, int B) {
  __shared__ char smem[LDS_TOTAL];
  unsigned short* rawp = (unsigned short*)(smem + RAW_OFF);
  unsigned short* stab = (unsigned short*)(smem + STAB_OFF);

  const unsigned short* w1t   = ws16;
  const unsigned short* w2t   = ws16 + 16384;
  const unsigned short* rhot  = ws16 + 81920;
  const unsigned short* headt = ws16 + 147456;

  const int tid = threadIdx.x;
  const int lane = tid & 63;
  const int wv = tid >> 6;       // 0..7
  const int l15 = lane & 15;
  const int lq = lane >> 4;      // 0..3
  const int wbase = wv * 32;     // 32-col N-strip
  const long brow = (long)blockIdx.x * 64;
  const f32x4 fzero = {0.f, 0.f, 0.f, 0.f};

  // ---- stage raw inputs as bf16 (once per block) ----
  for (int i = tid; i < 64 * 55; i += 512) {
    int r = i / 55, c = i - r * 55;
    rawp[r * 82 + c] = f2bf(obs[brow * 55 + i]);
  }
  for (int i = tid; i < 64 * 9; i += 512) {
    int r = i / 9, c = i - r * 9;
    rawp[r * 82 + 56 + c] = f2bf(ag[brow * 9 + i]);
    rawp[r * 82 + 65 + c] = f2bf(g[brow * 9 + i]);
  }
  if (tid < 64) {
    rawp[tid * 82 + 55] = 0;
    rawp[tid * 82 + 74] = 0;       // source of 0.0
    rawp[tid * 82 + 75] = 0x3F80;  // source of 1.0
  }
  // ---- s-tables for all 6 perms ----
  if (tid < 384) {
    const int PI[6] = {0, 0, 1, 1, 2, 2};
    const int PJ[6] = {1, 2, 0, 2, 0, 1};
    int p = tid >> 6, c = tid & 63;
    int pi = PI[p], pj = PJ[p], s;
    if (c < 3)       s = 56 + 3 * pi + c;
    else if (c < 6)  s = 56 + 3 * pj + (c - 3);
    else if (c < 9)  s = 65 + 3 * pi + (c - 6);
    else if (c < 12) s = 65 + 3 * pj + (c - 9);
    else if (c < 22) s = c - 12;
    else if (c < 25) s = ((c - 22) == pi) ? 75 : 74;
    else if (c < 40) s = 10 + 15 * pi + (c - 25);
    else if (c < 43) s = ((c - 40) == pj) ? 75 : 74;
    else if (c < 58) s = 10 + 15 * pj + (c - 43);
    else             s = 74;
    stab[tid] = (unsigned short)s;
  }

  // ---- per-wave bias fragments (n = wbase + nt*16 + lq*4 + r) ----
  f32x4 b1f[2], b2f[2];
#pragma unroll
  for (int nt = 0; nt < 2; nt++) {
    b1f[nt] = *(const f32x4*)&b1v[wbase + nt * 16 + lq * 4];
    b2f[nt] = *(const f32x4*)&b2v[wbase + nt * 16 + lq * 4];
  }

  f32x4 pooled[2][4];
#pragma unroll
  for (int a = 0; a < 2; a++)
#pragma unroll
    for (int b = 0; b < 4; b++) pooled[a][b] = fzero;

  __syncthreads();  // raw + stab ready

  for (int p = 0; p < 6; p++) {
    // ---- build inp tile: thread owns (row, col-octet); one b128 write ----
    {
      int r = tid >> 3, oct = tid & 7;
      u16x8 sv = *(const u16x8*)&stab[p * 64 + oct * 8];
      const unsigned short* rw = &rawp[r * 82];
      unsigned w0 = (unsigned)rw[sv[0]] | ((unsigned)rw[sv[1]] << 16);
      unsigned w1_ = (unsigned)rw[sv[2]] | ((unsigned)rw[sv[3]] << 16);
      unsigned w2_ = (unsigned)rw[sv[4]] | ((unsigned)rw[sv[5]] << 16);
      unsigned w3 = (unsigned)rw[sv[6]] | ((unsigned)rw[sv[7]] << 16);
      uint4 w = {w0, w1_, w2_, w3};
      *(uint4*)(smem + INP_OFF + swz128(r * 128 + oct * 16)) = w;
    }
    __syncthreads();  // inp ready; prev perm's hbuf reads all done

    // ---- GEMM1: h^T = W1_frag x inp_frag (+b1 in C-init) ----
    f32x4 acc1[2][4];
#pragma unroll
    for (int nt = 0; nt < 2; nt++)
#pragma unroll
      for (int mt = 0; mt < 4; mt++) acc1[nt][mt] = b1f[nt];
#pragma unroll
    for (int kk = 0; kk < 2; kk++) {
      bf16x8 wf[2], xf[4];
#pragma unroll
      for (int nt = 0; nt < 2; nt++)
        wf[nt] = *(const bf16x8*)&w1t[(wbase + nt * 16 + l15) * 64 + kk * 32 + lq * 8];
#pragma unroll
      for (int mt = 0; mt < 4; mt++)
        xf[mt] = *(const bf16x8*)(smem + INP_OFF +
                   swz128((mt * 16 + l15) * 128 + (kk * 32 + lq * 8) * 2));
#pragma unroll
      for (int nt = 0; nt < 2; nt++)
#pragma unroll
        for (int mt = 0; mt < 4; mt++)
          acc1[nt][mt] = mfma16(wf[nt], xf[mt], acc1[nt][mt]);
    }
    // lane holds h[m = mt*16+l15][k2 = wbase+nt*16+lq*4 + 0..3] -> b64 store
#pragma unroll
    for (int nt = 0; nt < 2; nt++)
#pragma unroll
      for (int mt = 0; mt < 4; mt++) {
        f32x4 h;
#pragma unroll
        for (int r = 0; r < 4; r++) h[r] = fmaxf(acc1[nt][mt][r], 0.f);
        *(uint2*)(smem + HB_OFF + swz512((mt * 16 + l15) * 512 +
                   (wbase + nt * 16 + lq * 4) * 2)) = pack4(h);
      }
    __syncthreads();  // hbuf ready

    // ---- GEMM2: (hW2)^T = W2_frag x h_frag (+b2 in C-init) ----
    f32x4 acc2[2][4];
#pragma unroll
    for (int nt = 0; nt < 2; nt++)
#pragma unroll
      for (int mt = 0; mt < 4; mt++) acc2[nt][mt] = b2f[nt];
#pragma unroll
    for (int kk = 0; kk < 8; kk++) {
      bf16x8 wf[2], hf[4];
#pragma unroll
      for (int nt = 0; nt < 2; nt++)
        wf[nt] = *(const bf16x8*)&w2t[(wbase + nt * 16 + l15) * 256 + kk * 32 + lq * 8];
#pragma unroll
      for (int mt = 0; mt < 4; mt++)
        hf[mt] = *(const bf16x8*)(smem + HB_OFF +
                   swz512((mt * 16 + l15) * 512 + (kk * 32 + lq * 8) * 2));
#pragma unroll
      for (int nt = 0; nt < 2; nt++)
#pragma unroll
        for (int mt = 0; mt < 4; mt++)
          acc2[nt][mt] = mfma16(wf[nt], hf[mt], acc2[nt][mt]);
    }
#pragma unroll
    for (int nt = 0; nt < 2; nt++)
#pragma unroll
      for (int mt = 0; mt < 4; mt++)
#pragma unroll
        for (int r = 0; r < 4; r++)
          pooled[nt][mt][r] += fmaxf(acc2[nt][mt][r], 0.f);
    // no barrier: next perm's post-build barrier orders hbuf overwrite after reads
  }

  __syncthreads();  // all GEMM2 reads done
  // ---- pooled -> hbuf (already >= 0) ----
#pragma unroll
  for (int nt = 0; nt < 2; nt++)
#pragma unroll
    for (int mt = 0; mt < 4; mt++)
      *(uint2*)(smem + HB_OFF + swz512((mt * 16 + l15) * 512 +
                 (wbase + nt * 16 + lq * 4) * 2)) = pack4(pooled[nt][mt]);
  __syncthreads();

  // ---- GEMM3: x^T = RHO_frag x pooled_frag (+rb in C-init) ----
  f32x4 rbf[2];
#pragma unroll
  for (int nt = 0; nt < 2; nt++)
    rbf[nt] = *(const f32x4*)&rbv[wbase + nt * 16 + lq * 4];
  f32x4 acc3[2][4];
#pragma unroll
  for (int nt = 0; nt < 2; nt++)
#pragma unroll
    for (int mt = 0; mt < 4; mt++) acc3[nt][mt] = rbf[nt];
#pragma unroll
  for (int kk = 0; kk < 8; kk++) {
    bf16x8 wf[2], hf[4];
#pragma unroll
    for (int nt = 0; nt < 2; nt++)
      wf[nt] = *(const bf16x8*)&rhot[(wbase + nt * 16 + l15) * 256 + kk * 32 + lq * 8];
#pragma unroll
    for (int mt = 0; mt < 4; mt++)
      hf[mt] = *(const bf16x8*)(smem + HB_OFF +
                 swz512((mt * 16 + l15) * 512 + (kk * 32 + lq * 8) * 2));
#pragma unroll
    for (int nt = 0; nt < 2; nt++)
#pragma unroll
      for (int mt = 0; mt < 4; mt++)
        acc3[nt][mt] = mfma16(wf[nt], hf[mt], acc3[nt][mt]);
  }
  __syncthreads();  // hbuf reads done before overwrite
#pragma unroll
  for (int nt = 0; nt < 2; nt++)
#pragma unroll
    for (int mt = 0; mt < 4; mt++) {
      f32x4 x;
#pragma unroll
      for (int r = 0; r < 4; r++) x[r] = fmaxf(acc3[nt][mt][r], 0.f);
      *(uint2*)(smem + HB_OFF + swz512((mt * 16 + l15) * 512 +
                 (wbase + nt * 16 + lq * 4) * 2)) = pack4(x);
    }
  __syncthreads();

  // ---- GEMM4: heads^T = HEAD_frag x x_frag; waves 0-3 own 16 rows each ----
  if (wv < 4) {
    f32x4 acc4 = fzero;
    if (lq == 0)      acc4 = *(const f32x4*)mbv;
    else if (lq == 1) acc4 = *(const f32x4*)lbv;
#pragma unroll
    for (int kk = 0; kk < 8; kk++) {
      bf16x8 hf = *(const bf16x8*)(smem + HB_OFF +
                    swz512((wv * 16 + l15) * 512 + (kk * 32 + lq * 8) * 2));
      bf16x8 wf = *(const bf16x8*)&headt[l15 * 256 + kk * 32 + lq * 8];
      acc4 = mfma16(wf, hf, acc4);
    }
    long gr = brow + wv * 16 + l15;   // lane holds out[gr][n = lq*4 + 0..3]
    if (lq == 0) {
      *(f32x4*)&out[gr * 4] = acc4;   // mean row, float4
    } else if (lq == 1) {
      f32x4 u;
#pragma unroll
      for (int r = 0; r < 4; r++) u[r] = fminf(fmaxf(acc4[r], -20.f), 2.f);
      *(f32x4*)&out[(long)B * 4 + gr * 4] = u;  // logstd row, float4
    }
  }
}

extern "C" void kernel_launch(void* const* d_in, const int* in_sizes, int n_in,
                              void* d_out, int out_size, void* d_ws, size_t ws_size,
                              hipStream_t stream) {
  const float* obs = (const float*)d_in[0];
  const float* ag  = (const float*)d_in[1];
  const float* g   = (const float*)d_in[2];
  const float* w1  = (const float*)d_in[3];
  const float* b1  = (const float*)d_in[4];
  const float* w2  = (const float*)d_in[5];
  const float* b2  = (const float*)d_in[6];
  const float* rw  = (const float*)d_in[7];
  const float* rb  = (const float*)d_in[8];
  const float* mw  = (const float*)d_in[9];
  const float* mb  = (const float*)d_in[10];
  const float* lw  = (const float*)d_in[11];
  const float* lb  = (const float*)d_in[12];
  int B = in_sizes[0] / 55;

  unsigned short* ws16 = (unsigned short*)d_ws;
  hipLaunchKernelGGL(actor_prep, dim3(128), dim3(256), 0, stream, w1, w2, rw, mw, lw, ws16);
  hipLaunchKernelGGL(actor_main, dim3(B / 64), dim3(512), 0, stream,
                     obs, ag, g, b1, b2, rb, mb, lb, ws16, (float*)d_out, B);
}

// Round 6
// 112.836 us; speedup vs baseline: 1.3557x; 1.3557x over previous
//
#include <hip/hip_runtime.h>

// Deep-Sets actor, round 6: W2-strip persistent in VGPRs, persistent blocks.
// grid=256 x 512 thr (8 waves, 1 block/CU), each block loops 4 tiles of M=64.
// Wave owns a 32-col N-strip; its W2T strip (32x256) lives in 16 bf16x8 regs.
// Per perm: phaseA = GEMM1 (inp->hbuf); phaseB = GEMM2 (regs x hbuf) + build(p+1).
// inp double-buffered so build overlaps GEMM2. 2 barriers/perm.

typedef __bf16 bf16x8 __attribute__((ext_vector_type(8)));
typedef float f32x4 __attribute__((ext_vector_type(4)));
typedef unsigned short u16x8 __attribute__((ext_vector_type(8)));

#define HB_OFF   0        // hbuf: 64 rows x 512 B, XOR-swizzled      (32768)
#define INP0_OFF 32768    // inp buf 0: 64 rows x 128 B, swizzled     ( 8192)
#define INP1_OFF 40960    // inp buf 1                                ( 8192)
#define RAW_OFF  49152    // raw: 64 rows x 82 bf16                   (10496)
#define STAB_OFF 59648    // s-tables: 6 perms x 64 u16               (  768)
#define LDS_TOTAL 60416

__device__ __forceinline__ unsigned short f2bf(float f) {
  union { float f; unsigned u; } v; v.f = f;
  unsigned r = v.u + 0x7fffu + ((v.u >> 16) & 1u);  // RNE
  return (unsigned short)(r >> 16);
}
__device__ __forceinline__ int swz512(int o) { return o ^ (((o >> 9) & 7) << 4); }
__device__ __forceinline__ int swz128(int o) { return o ^ (((o >> 7) & 7) << 4); }
__device__ __forceinline__ f32x4 mfma16(bf16x8 a, bf16x8 b, f32x4 c) {
  return __builtin_amdgcn_mfma_f32_16x16x32_bf16(a, b, c, 0, 0, 0);
}
__device__ __forceinline__ uint2 pack4(f32x4 v) {  // 4 f32 -> 4 bf16 (RNE)
  uint2 r;
  asm("v_cvt_pk_bf16_f32 %0, %1, %2" : "=v"(r.x) : "v"(v[0]), "v"(v[1]));
  asm("v_cvt_pk_bf16_f32 %0, %1, %2" : "=v"(r.y) : "v"(v[2]), "v"(v[3]));
  return r;
}

__global__ void actor_prep(const float* __restrict__ w1, const float* __restrict__ w2,
                           const float* __restrict__ rho, const float* __restrict__ mw,
                           const float* __restrict__ lw, unsigned short* __restrict__ ws16) {
  int idx = blockIdx.x * blockDim.x + threadIdx.x;
  const int T = 16384 + 65536 + 65536 + 4096;
  for (; idx < T; idx += gridDim.x * blockDim.x) {
    float v;
    if (idx < 16384) {                 // W1T[n][k], k padded 58->64
      int n = idx >> 6, k = idx & 63;
      v = (k < 58) ? w1[k * 256 + n] : 0.f;
    } else if (idx < 81920) {          // W2T[n][k]
      int o = idx - 16384; int n = o >> 8, k = o & 255;
      v = w2[k * 256 + n];
    } else if (idx < 147456) {         // RHOT[n][k]
      int o = idx - 81920; int n = o >> 8, k = o & 255;
      v = rho[k * 256 + n];
    } else {                           // HEADT[n][k]
      int o = idx - 147456; int n = o >> 8, k = o & 255;
      v = (n < 4) ? mw[k * 4 + n] : ((n < 8) ? lw[k * 4 + (n - 4)] : 0.f);
    }
    ws16[idx] = f2bf(v);
  }
}

__global__ __launch_bounds__(512, 1) void actor_main(
    const float* __restrict__ obs, const float* __restrict__ ag, const float* __restrict__ g,
    const float* __restrict__ b1v, const float* __restrict__ b2v, const float* __restrict__ rbv,
    const float* __restrict__ mbv, const float* __restrict__ lbv,
    const unsigned short* __restrict__ ws16,
    float* __restrict__ out, int B) {
  __shared__ char smem[LDS_TOTAL];
  unsigned short* rawp = (unsigned short*)(smem + RAW_OFF);
  unsigned short* stab = (unsigned short*)(smem + STAB_OFF);

  const unsigned short* w1t   = ws16;
  const unsigned short* w2t   = ws16 + 16384;
  const unsigned short* rhot  = ws16 + 81920;
  const unsigned short* headt = ws16 + 147456;

  const int tid = threadIdx.x;
  const int lane = tid & 63;
  const int wv = tid >> 6;       // 0..7
  const int l15 = lane & 15;
  const int lq = lane >> 4;      // 0..3
  const int wbase = wv * 32;     // 32-col N-strip
  const int ntiles = B / 64;
  const f32x4 fzero = {0.f, 0.f, 0.f, 0.f};

  // ---- persistent register state (whole kernel) ----
  bf16x8 wf2[8][2];              // W2T strip: 64 VGPR
#pragma unroll
  for (int kk = 0; kk < 8; kk++)
#pragma unroll
    for (int nt = 0; nt < 2; nt++)
      wf2[kk][nt] = *(const bf16x8*)&w2t[(wbase + nt * 16 + l15) * 256 + kk * 32 + lq * 8];
  bf16x8 w1r[2][2];              // W1T strip: 16 VGPR
#pragma unroll
  for (int nt = 0; nt < 2; nt++)
#pragma unroll
    for (int kk = 0; kk < 2; kk++)
      w1r[nt][kk] = *(const bf16x8*)&w1t[(wbase + nt * 16 + l15) * 64 + kk * 32 + lq * 8];
  f32x4 b1f[2], b2f[2], rbf[2];
#pragma unroll
  for (int nt = 0; nt < 2; nt++) {
    b1f[nt] = *(const f32x4*)&b1v[wbase + nt * 16 + lq * 4];
    b2f[nt] = *(const f32x4*)&b2v[wbase + nt * 16 + lq * 4];
    rbf[nt] = *(const f32x4*)&rbv[wbase + nt * 16 + lq * 4];
  }
  f32x4 mb4 = *(const f32x4*)mbv;
  f32x4 lb4 = *(const f32x4*)lbv;

  // ---- s-tables once per block ----
  if (tid < 384) {
    const int PI[6] = {0, 0, 1, 1, 2, 2};
    const int PJ[6] = {1, 2, 0, 2, 0, 1};
    int p = tid >> 6, c = tid & 63;
    int pi = PI[p], pj = PJ[p], s;
    if (c < 3)       s = 56 + 3 * pi + c;
    else if (c < 6)  s = 56 + 3 * pj + (c - 3);
    else if (c < 9)  s = 65 + 3 * pi + (c - 6);
    else if (c < 12) s = 65 + 3 * pj + (c - 9);
    else if (c < 22) s = c - 12;
    else if (c < 25) s = ((c - 22) == pi) ? 75 : 74;
    else if (c < 40) s = 10 + 15 * pi + (c - 25);
    else if (c < 43) s = ((c - 40) == pj) ? 75 : 74;
    else if (c < 58) s = 10 + 15 * pj + (c - 43);
    else             s = 74;
    stab[tid] = (unsigned short)s;
  }

  for (int t = blockIdx.x; t < ntiles; t += gridDim.x) {
    const long brow = (long)t * 64;

    // ---- stage raw inputs as bf16 ----
    for (int i = tid; i < 64 * 55; i += 512) {
      int r = i / 55, c = i - r * 55;
      rawp[r * 82 + c] = f2bf(obs[brow * 55 + i]);
    }
    for (int i = tid; i < 64 * 9; i += 512) {
      int r = i / 9, c = i - r * 9;
      rawp[r * 82 + 56 + c] = f2bf(ag[brow * 9 + i]);
      rawp[r * 82 + 65 + c] = f2bf(g[brow * 9 + i]);
    }
    if (tid < 64) {
      rawp[tid * 82 + 55] = 0;
      rawp[tid * 82 + 74] = 0;       // source of 0.0
      rawp[tid * 82 + 75] = 0x3F80;  // source of 1.0
    }
    __syncthreads();  // raw (+stab on first tile) ready; prev tile's hbuf reads done

    // ---- build(0) into inp0 ----
    {
      int r = tid >> 3, oct = tid & 7;
      u16x8 sv = *(const u16x8*)&stab[0 * 64 + oct * 8];
      const unsigned short* rw = &rawp[r * 82];
      uint4 w;
      w.x = (unsigned)rw[sv[0]] | ((unsigned)rw[sv[1]] << 16);
      w.y = (unsigned)rw[sv[2]] | ((unsigned)rw[sv[3]] << 16);
      w.z = (unsigned)rw[sv[4]] | ((unsigned)rw[sv[5]] << 16);
      w.w = (unsigned)rw[sv[6]] | ((unsigned)rw[sv[7]] << 16);
      *(uint4*)(smem + INP0_OFF + swz128(r * 128 + oct * 16)) = w;
    }
    __syncthreads();

    f32x4 pooled[2][4];
#pragma unroll
    for (int a = 0; a < 2; a++)
#pragma unroll
      for (int b = 0; b < 4; b++) pooled[a][b] = fzero;

    for (int p = 0; p < 6; p++) {
      const int ib = (p & 1) ? INP1_OFF : INP0_OFF;
      // ---- phaseA: GEMM1(p) ----
      f32x4 acc1[2][4];
#pragma unroll
      for (int nt = 0; nt < 2; nt++)
#pragma unroll
        for (int mt = 0; mt < 4; mt++) acc1[nt][mt] = b1f[nt];
#pragma unroll
      for (int kk = 0; kk < 2; kk++) {
        bf16x8 xf[4];
#pragma unroll
        for (int mt = 0; mt < 4; mt++)
          xf[mt] = *(const bf16x8*)(smem + ib +
                     swz128((mt * 16 + l15) * 128 + (kk * 32 + lq * 8) * 2));
#pragma unroll
        for (int nt = 0; nt < 2; nt++)
#pragma unroll
          for (int mt = 0; mt < 4; mt++)
            acc1[nt][mt] = mfma16(w1r[nt][kk], xf[mt], acc1[nt][mt]);
      }
#pragma unroll
      for (int nt = 0; nt < 2; nt++)
#pragma unroll
        for (int mt = 0; mt < 4; mt++) {
          f32x4 h;
#pragma unroll
          for (int r = 0; r < 4; r++) h[r] = fmaxf(acc1[nt][mt][r], 0.f);
          *(uint2*)(smem + HB_OFF + swz512((mt * 16 + l15) * 512 +
                     (wbase + nt * 16 + lq * 4) * 2)) = pack4(h);
        }
      __syncthreads();  // hbuf ready

      // ---- phaseB: build(p+1) overlapped with GEMM2(p) ----
      if (p < 5) {
        int r = tid >> 3, oct = tid & 7;
        u16x8 sv = *(const u16x8*)&stab[(p + 1) * 64 + oct * 8];
        const unsigned short* rw = &rawp[r * 82];
        uint4 w;
        w.x = (unsigned)rw[sv[0]] | ((unsigned)rw[sv[1]] << 16);
        w.y = (unsigned)rw[sv[2]] | ((unsigned)rw[sv[3]] << 16);
        w.z = (unsigned)rw[sv[4]] | ((unsigned)rw[sv[5]] << 16);
        w.w = (unsigned)rw[sv[6]] | ((unsigned)rw[sv[7]] << 16);
        *(uint4*)(smem + ((p & 1) ? INP0_OFF : INP1_OFF) + swz128(r * 128 + oct * 16)) = w;
      }
      f32x4 acc2[2][4];
#pragma unroll
      for (int nt = 0; nt < 2; nt++)
#pragma unroll
        for (int mt = 0; mt < 4; mt++) acc2[nt][mt] = b2f[nt];
      __builtin_amdgcn_s_setprio(1);
#pragma unroll
      for (int kk = 0; kk < 8; kk++) {
        bf16x8 hf[4];
#pragma unroll
        for (int mt = 0; mt < 4; mt++)
          hf[mt] = *(const bf16x8*)(smem + HB_OFF +
                     swz512((mt * 16 + l15) * 512 + (kk * 32 + lq * 8) * 2));
#pragma unroll
        for (int nt = 0; nt < 2; nt++)
#pragma unroll
          for (int mt = 0; mt < 4; mt++)
            acc2[nt][mt] = mfma16(wf2[kk][nt], hf[mt], acc2[nt][mt]);
      }
      __builtin_amdgcn_s_setprio(0);
#pragma unroll
      for (int nt = 0; nt < 2; nt++)
#pragma unroll
        for (int mt = 0; mt < 4; mt++)
#pragma unroll
          for (int r = 0; r < 4; r++)
            pooled[nt][mt][r] += fmaxf(acc2[nt][mt][r], 0.f);
      __syncthreads();  // GEMM2 hbuf reads done -> next phaseA may overwrite
    }

    // ---- pooled -> hbuf ----
#pragma unroll
    for (int nt = 0; nt < 2; nt++)
#pragma unroll
      for (int mt = 0; mt < 4; mt++)
        *(uint2*)(smem + HB_OFF + swz512((mt * 16 + l15) * 512 +
                   (wbase + nt * 16 + lq * 4) * 2)) = pack4(pooled[nt][mt]);
    __syncthreads();

    // ---- GEMM3: x = relu(rho x pooled + rb); rho streamed (once per tile) ----
    f32x4 acc3[2][4];
#pragma unroll
    for (int nt = 0; nt < 2; nt++)
#pragma unroll
      for (int mt = 0; mt < 4; mt++) acc3[nt][mt] = rbf[nt];
#pragma unroll
    for (int kk = 0; kk < 8; kk++) {
      bf16x8 wf[2], hf[4];
#pragma unroll
      for (int nt = 0; nt < 2; nt++)
        wf[nt] = *(const bf16x8*)&rhot[(wbase + nt * 16 + l15) * 256 + kk * 32 + lq * 8];
#pragma unroll
      for (int mt = 0; mt < 4; mt++)
        hf[mt] = *(const bf16x8*)(smem + HB_OFF +
                   swz512((mt * 16 + l15) * 512 + (kk * 32 + lq * 8) * 2));
#pragma unroll
      for (int nt = 0; nt < 2; nt++)
#pragma unroll
        for (int mt = 0; mt < 4; mt++)
          acc3[nt][mt] = mfma16(wf[nt], hf[mt], acc3[nt][mt]);
    }
    __syncthreads();  // hbuf reads done before overwrite
#pragma unroll
    for (int nt = 0; nt < 2; nt++)
#pragma unroll
      for (int mt = 0; mt < 4; mt++) {
        f32x4 x;
#pragma unroll
        for (int r = 0; r < 4; r++) x[r] = fmaxf(acc3[nt][mt][r], 0.f);
        *(uint2*)(smem + HB_OFF + swz512((mt * 16 + l15) * 512 +
                   (wbase + nt * 16 + lq * 4) * 2)) = pack4(x);
      }
    __syncthreads();

    // ---- GEMM4: heads; waves 0-3 own 16 rows each ----
    if (wv < 4) {
      f32x4 acc4 = fzero;
      if (lq == 0)      acc4 = mb4;
      else if (lq == 1) acc4 = lb4;
#pragma unroll
      for (int kk = 0; kk < 8; kk++) {
        bf16x8 hf = *(const bf16x8*)(smem + HB_OFF +
                      swz512((wv * 16 + l15) * 512 + (kk * 32 + lq * 8) * 2));
        bf16x8 wf = *(const bf16x8*)&headt[l15 * 256 + kk * 32 + lq * 8];
        acc4 = mfma16(wf, hf, acc4);
      }
      long gr = brow + wv * 16 + l15;   // lane holds out[gr][lq*4 + 0..3]
      if (lq == 0) {
        *(f32x4*)&out[gr * 4] = acc4;
      } else if (lq == 1) {
        f32x4 u;
#pragma unroll
        for (int r = 0; r < 4; r++) u[r] = fminf(fmaxf(acc4[r], -20.f), 2.f);
        *(f32x4*)&out[(long)B * 4 + gr * 4] = u;
      }
    }
    // tile-top __syncthreads (after raw staging) orders GEMM4 hbuf reads
    // before next tile's phaseA hbuf writes.
  }
}

extern "C" void kernel_launch(void* const* d_in, const int* in_sizes, int n_in,
                              void* d_out, int out_size, void* d_ws, size_t ws_size,
                              hipStream_t stream) {
  const float* obs = (const float*)d_in[0];
  const float* ag  = (const float*)d_in[1];
  const float* g   = (const float*)d_in[2];
  const float* w1  = (const float*)d_in[3];
  const float* b1  = (const float*)d_in[4];
  const float* w2  = (const float*)d_in[5];
  const float* b2  = (const float*)d_in[6];
  const float* rw  = (const float*)d_in[7];
  const float* rb  = (const float*)d_in[8];
  const float* mw  = (const float*)d_in[9];
  const float* mb  = (const float*)d_in[10];
  const float* lw  = (const float*)d_in[11];
  const float* lb  = (const float*)d_in[12];
  int B = in_sizes[0] / 55;

  unsigned short* ws16 = (unsigned short*)d_ws;
  hipLaunchKernelGGL(actor_prep, dim3(128), dim3(256), 0, stream, w1, w2, rw, mw, lw, ws16);
  hipLaunchKernelGGL(actor_main, dim3(256), dim3(512), 0, stream,
                     obs, ag, g, b1, b2, rb, mb, lb, ws16, (float*)d_out, B);
}